// Round 11
// baseline (682.944 us; speedup 1.0000x reference)
//
#include <hip/hip_runtime.h>
#include <hip/hip_fp16.h>
#include <math.h>

#define N_ENT  150000
#define N_USR  60000
#define CDIM   64
#define NE     1000000
#define NNZV   1000000
#define NREL9  9                        // weight rows incl. np-wrap row 8
#define NTOT   (2 * N_ENT + N_USR)      // 360000 concatenated segment counters
#define TOTAL_ITEMS (NE + 2 * NNZV)     // 3000000 (scan sentinel)
#define SCAN_B ((NTOT + 1023) / 1024)   // 352 scan blocks

#define EG (N_ENT / 4)                  // 37500 entity blocks (4 waves each)
#define UG (N_USR / 4)                  // 15000 user blocks
#define UCVT ((N_USR * CDIM / 2 + 255) / 256)  // 7500 usr-cvt blocks

// ---- LDS histogram/scatter geometry (fully atomic-free CSR build) --------
// R9/R10 finding: device-scope atomicAdd ~ 32B write-through on gfx950;
// 3M atomics = ~94MB HBM writes. Both hist AND scatter now use LDS only.
#define SLICE_K 16384                   // counters per slice (64KB LDS)
#define SH 10                           // head slices  (10*16384 >= 150000)
#define SC 10                           // col slices
#define SR 4                            // row slices   (4*16384 >= 60000)
#define NSLICE (SH + SC + SR)           // 24
#define ESPLIT 16                       // edge-chunks per slice
#define ECH (NE / ESPLIT)               // 62500 (exact, %4==0)
#define HIST_BLKS (NSLICE * ESPLIT)     // 384 blocks
#define RB ((NTOT + 255) / 256)         // 1407 reduce blocks

// ---- DPP wave reductions (VALU pipe, no LDS) ----------------------------
template <int CTRL>
__device__ __forceinline__ float dpp_addf(float v) {
    int iv = __float_as_int(v);
    int x = __builtin_amdgcn_update_dpp(iv, iv, CTRL, 0xF, 0xF, true);
    return v + __int_as_float(x);
}
template <int CTRL>
__device__ __forceinline__ float dpp_maxf(float v) {
    int iv = __float_as_int(v);
    int x = __builtin_amdgcn_update_dpp(iv, iv, CTRL, 0xF, 0xF, true);
    return fmaxf(v, __int_as_float(x));
}
__device__ __forceinline__ float wave_sum(float v) {
    v = dpp_addf<0x111>(v);   // row_shr:1
    v = dpp_addf<0x112>(v);   // row_shr:2
    v = dpp_addf<0x114>(v);   // row_shr:4
    v = dpp_addf<0x118>(v);   // row_shr:8
    v = dpp_addf<0x142>(v);   // row_bcast:15
    v = dpp_addf<0x143>(v);   // row_bcast:31
    return __int_as_float(__builtin_amdgcn_readlane(__float_as_int(v), 63));
}
__device__ __forceinline__ float wave_max(float v) {
    v = dpp_maxf<0x111>(v);
    v = dpp_maxf<0x112>(v);
    v = dpp_maxf<0x114>(v);
    v = dpp_maxf<0x118>(v);
    v = dpp_maxf<0x142>(v);
    v = dpp_maxf<0x143>(v);
    return __int_as_float(__builtin_amdgcn_readlane(__float_as_int(v), 63));
}

__device__ __forceinline__ float bcast_f(float v, int l) { return __int_as_float(__builtin_amdgcn_readlane(__float_as_int(v), l)); }

// Block-wide exclusive scan (blockDim multiple of 64, <=1024). lds: >=16 ints.
__device__ __forceinline__ int block_excl_scan(int v, int* lds) {
    int lane = threadIdx.x & 63, wid = threadIdx.x >> 6;
    int incl = v;
#pragma unroll
    for (int o = 1; o < 64; o <<= 1) {
        int t = __shfl_up(incl, o, 64);
        if (lane >= o) incl += t;
    }
    if (lane == 63) lds[wid] = incl;
    __syncthreads();
    int nw = blockDim.x >> 6;
    if ((int)threadIdx.x < nw) {
        int s = lds[threadIdx.x];
        int si = s;
        for (int o = 1; o < nw; o <<= 1) {
            int t = __shfl_up(si, o, 64);
            if ((int)threadIdx.x >= o) si += t;
        }
        lds[threadIdx.x] = si - s;  // exclusive offset for this wave
    }
    __syncthreads();
    return incl - v + lds[wid];
}

// ---- Atomic-free histogram: block (sid, chunk) owns one 16K-counter slice
// in LDS, scans 1/16 of its key array, flushes via plain stores to priv.
__global__ __launch_bounds__(256) void k_hist_lds(
    const int* __restrict__ head, const int* __restrict__ cols,
    const int* __restrict__ rows, int* __restrict__ priv)
{
    __shared__ int h[SLICE_K];
    int sid = blockIdx.x >> 4, chunk = blockIdx.x & (ESPLIT - 1);
    const int* key; int k0;
    if (sid < SH)            { key = head; k0 = sid * SLICE_K; }
    else if (sid < SH + SC)  { key = cols; k0 = (sid - SH) * SLICE_K; }
    else                     { key = rows; k0 = (sid - SH - SC) * SLICE_K; }
    for (int t = threadIdx.x; t < SLICE_K; t += 256) h[t] = 0;
    __syncthreads();
    const int4* key4 = (const int4*)(key + chunk * ECH);   // ECH % 4 == 0
    for (int i = threadIdx.x; i < ECH / 4; i += 256) {
        int4 k4 = key4[i];
        int a = k4.x - k0, b = k4.y - k0, c = k4.z - k0, d = k4.w - k0;
        if ((unsigned)a < (unsigned)SLICE_K) atomicAdd(&h[a], 1);
        if ((unsigned)b < (unsigned)SLICE_K) atomicAdd(&h[b], 1);
        if ((unsigned)c < (unsigned)SLICE_K) atomicAdd(&h[c], 1);
        if ((unsigned)d < (unsigned)SLICE_K) atomicAdd(&h[d], 1);
    }
    __syncthreads();
    int* dst = priv + (size_t)blockIdx.x * SLICE_K;
    for (int t = threadIdx.x; t < SLICE_K; t += 256) dst[t] = h[t];
}

// ---- Fused chunk-scan + hop-1 prep: blocks [0,RB) turn the per-chunk
// counts into EXCLUSIVE per-chunk offsets (in place) + total into cnt
// (enables the atomic-free scatter); [RB,RB+EG) entity fp16 cvt + sq;
// rest usr fp16 cvt.
__global__ __launch_bounds__(256) void k_prepreduce(
    int* __restrict__ priv, int* __restrict__ cnt,
    const float* __restrict__ ent, const float* __restrict__ usr,
    const float* __restrict__ wt,
    __half* __restrict__ ent16, __half* __restrict__ usr16,
    float* __restrict__ sq)
{
    int b = blockIdx.x;
    if (b < RB) {
        int i = b * 256 + (int)threadIdx.x;
        if (i >= NTOT) return;
        int sid, local;
        if (i < N_ENT)          { sid = i >> 14;                    local = i & (SLICE_K - 1); }
        else if (i < 2 * N_ENT) { int j = i - N_ENT;     sid = SH + (j >> 14);      local = j & (SLICE_K - 1); }
        else                    { int j = i - 2 * N_ENT; sid = SH + SC + (j >> 14); local = j & (SLICE_K - 1); }
        int* p = priv + (size_t)(sid * ESPLIT) * SLICE_K + local;
        int s = 0;
#pragma unroll
        for (int c = 0; c < ESPLIT; ++c) {
            int t = p[(size_t)c * SLICE_K];
            p[(size_t)c * SLICE_K] = s;        // exclusive chunk offset
            s += t;
        }
        cnt[i] = s;
    } else if (b < RB + EG) {
        int e = ((b - RB) * 256 + (int)threadIdx.x) >> 6;
        int lane = threadIdx.x & 63;
        float own = ent[(e << 6) + lane];
        ent16[(e << 6) + lane] = __float2half(own);
        float o2 = own * own;
        float mine = 0.f;
#pragma unroll
        for (int rt = 0; rt < NREL9; ++rt) {
            float r = wt[(rt << 6) + lane];
            float s = wave_sum(o2 * r * r);
            if (lane == rt) mine = s;
        }
        if (lane < NREL9) sq[e * NREL9 + lane] = mine;
    } else {
        int i = (b - RB - EG) * 256 + (int)threadIdx.x;   // float2 index
        if (i < N_USR * CDIM / 2) {
            float2 v = ((const float2*)usr)[i];
            ((__half2*)usr16)[i] = __floats2half2_rn(v.x, v.y);
        }
    }
}

__global__ __launch_bounds__(1024) void k_bsum(
    const int* __restrict__ cnt, int* __restrict__ bsum)
{
    __shared__ int lds[16];
    int i = blockIdx.x * 1024 + threadIdx.x;
    float v = (i < NTOT) ? (float)cnt[i] : 0.f;
    float s = wave_sum(v);                 // exact: block total <= 3M < 2^24
    int lane = threadIdx.x & 63, wid = threadIdx.x >> 6;
    if (lane == 0) lds[wid] = (int)s;
    __syncthreads();
    if (threadIdx.x == 0) {
        int t = 0;
        for (int k = 0; k < 16; ++k) t += lds[k];
        bsum[blockIdx.x] = t;
    }
}

__global__ __launch_bounds__(512) void k_scan_small(int* __restrict__ bsum)
{
    __shared__ int lds[16];
    int i = threadIdx.x;
    int v = (i < SCAN_B) ? bsum[i] : 0;
    int e = block_excl_scan(v, lds);
    if (i < SCAN_B) bsum[i] = e;
}

// start[i] = exclusive prefix (immutable); start[NTOT] = sentinel.
// No cursor array anymore — scatter derives ranks from priv chunk offsets.
__global__ __launch_bounds__(1024) void k_scan_apply(
    const int* __restrict__ cnt, const int* __restrict__ bsum,
    int* __restrict__ start)
{
    __shared__ int lds[16];
    int i = blockIdx.x * 1024 + threadIdx.x;
    int v = (i < NTOT) ? cnt[i] : 0;
    int e = block_excl_scan(v, lds) + bsum[blockIdx.x];
    if (i < NTOT) start[i] = e;
    else if (i == NTOT) start[i] = TOTAL_ITEMS;
}

// ---- Atomic-free scatter: block (sid, chunk) loads cur[t] = start[ctr] +
// per-chunk exclusive offset into LDS, claims ranks with LDS atomics
// (intra-counter order arbitrary, same as before), writes payload with
// plain stores. (counter, chunk) output regions are disjoint -> no races;
// each block's writes land in a ~1MB contiguous slice range -> full lines.
__global__ __launch_bounds__(256) void k_scatter_lds(
    const int* __restrict__ head, const int* __restrict__ tail,
    const int* __restrict__ etype,
    const int* __restrict__ rows, const int* __restrict__ cols,
    const float* __restrict__ vals,
    const int* __restrict__ start, const int* __restrict__ priv,
    int* __restrict__ pk_h,                  // tail | rt<<18, sorted by head
    int2* __restrict__ rc,                   // (row, valbits) sorted by col
    int2* __restrict__ cv)                   // (col, valbits) sorted by row
{
    __shared__ int cur[SLICE_K];
    int sid = blockIdx.x >> 4, chunk = blockIdx.x & (ESPLIT - 1);
    const int* poff = priv + (size_t)(sid * ESPLIT + chunk) * SLICE_K;
    int e0 = chunk * ECH, e1 = e0 + ECH;

    if (sid < SH) {
        int k0 = sid * SLICE_K;
        for (int t = threadIdx.x; t < SLICE_K; t += 256) {
            int g = k0 + t;
            cur[t] = (g < N_ENT) ? (start[g] + poff[t]) : 0;
        }
        __syncthreads();
        for (int i = e0 + (int)threadIdx.x; i < e1; i += 256) {
            int a = head[i] - k0;
            if ((unsigned)a < (unsigned)SLICE_K) {
                int rt = etype[i] - 1;
                if (rt < 0) rt = 8;          // weight[-1] -> row 8 (np wrap)
                int p = atomicAdd(&cur[a], 1);
                if ((unsigned)p < (unsigned)NE) pk_h[p] = tail[i] | (rt << 18);
            }
        }
    } else if (sid < SH + SC) {
        int k0 = (sid - SH) * SLICE_K;
        for (int t = threadIdx.x; t < SLICE_K; t += 256) {
            int g = k0 + t;
            cur[t] = (g < N_ENT) ? (start[N_ENT + g] - NE + poff[t]) : 0;
        }
        __syncthreads();
        for (int i = e0 + (int)threadIdx.x; i < e1; i += 256) {
            int a = cols[i] - k0;
            if ((unsigned)a < (unsigned)SLICE_K) {
                int p = atomicAdd(&cur[a], 1);
                if ((unsigned)p < (unsigned)NNZV)
                    rc[p] = make_int2(rows[i], __float_as_int(vals[i]));
            }
        }
    } else {
        int k0 = (sid - SH - SC) * SLICE_K;
        for (int t = threadIdx.x; t < SLICE_K; t += 256) {
            int g = k0 + t;
            cur[t] = (g < N_USR) ? (start[2 * N_ENT + g] - 2 * NE + poff[t]) : 0;
        }
        __syncthreads();
        for (int i = e0 + (int)threadIdx.x; i < e1; i += 256) {
            int a = rows[i] - k0;
            if ((unsigned)a < (unsigned)SLICE_K) {
                int p = atomicAdd(&cur[a], 1);
                if ((unsigned)p < (unsigned)NNZV)
                    cv[p] = make_int2(cols[i], __float_as_int(vals[i]));
            }
        }
    }
}

// ---- Fused per-hop kernel: blocks [0,EG) = entity role, rest = user. ----
// e/u hoisted to SGPR via readfirstlane -> segment bounds and descriptor
// addresses provably wave-uniform -> rc/cv/pk_h broadcast reads are SMEM
// s_load. The pk gather loop keeps ONE readlane per edge (wk from exp).
template <bool FIRST, bool LAST>
__global__ __launch_bounds__(256) void k_hop(
    const __half* __restrict__ ent16_cur, const __half* __restrict__ usr16_cur,
    const float* __restrict__ ent_res_base, const float* __restrict__ usr_res_base,
    const float* __restrict__ wt, const int* __restrict__ start,
    const int* __restrict__ pk_h, const float* __restrict__ sq_in,
    const int2* __restrict__ rc, const int2* __restrict__ cv,
    __half* __restrict__ ent16_next, __half* __restrict__ usr16_next,
    float* __restrict__ sq_out,
    float* __restrict__ out_ent, float* __restrict__ out_usr)
{
    int lane = threadIdx.x & 63;
    int b = blockIdx.x;

    if (b < EG) {
        // ================= entity role: one wave per entity ==============
        int e = __builtin_amdgcn_readfirstlane((b * 256 + (int)threadIdx.x) >> 6);

        // --- softmax-weighted neighbor aggregation, edges head == e ---
        int s1 = min(start[e + 1], NE);
        int s0 = min(start[e], s1);
        float m = 0.f, l = 0.f, acc = 0.f;    // att >= 0 so m=0 init exact
        for (int base = s0; base < s1; base += 64) {
            int j = base + lane;
            int cnt = min(64, s1 - base);
            float att = 0.f;
            if (j < s1) {                      // coalesced descriptor load
                int pk = pk_h[j];
                int t = pk & 0x3FFFF, rt = (pk >> 18) & 15;
                att = sq_in[e * NREL9 + rt] * sq_in[t * NREL9 + rt];
            }
            float mn = fmaxf(m, wave_max(att));
            float scale = __expf(m - mn);      // first chunk multiplies zeros
            float p = (j < s1) ? __expf(att - mn) : 0.f;
            l = l * scale + wave_sum(p);
            acc *= scale;
            m = mn;
            int k = 0;
            for (; k + 4 <= cnt; k += 4) {     // 4 independent gathers in flight
#pragma unroll
                for (int q = 0; q < 4; ++q) {
                    int pkk = pk_h[base + k + q];          // uniform -> s_load
                    float wk = bcast_f(p, k + q);
                    const __half* tp = ent16_cur + ((pkk & 0x3FFFF) << 6);
                    const float*  wp = wt + (((pkk >> 18) & 15) << 6);
                    acc += wk * __half2float(tp[lane]) * wp[lane];
                }
            }
            for (; k < cnt; ++k) {
                int pkk = pk_h[base + k];                  // uniform -> s_load
                float wk = bcast_f(p, k);
                const __half* tp = ent16_cur + ((pkk & 0x3FFFF) << 6);
                const float*  wp = wt + (((pkk >> 18) & 15) << 6);
                acc += wk * __half2float(tp[lane]) * wp[lane];
            }
        }
        float agg = (l > 0.f) ? acc / l : 0.f;

        // --- + interact_mat^T @ user_emb  (nnz with col == e) ---
        int c1 = min(start[N_ENT + e + 1] - NE, NNZV);
        int c0 = max(min(start[N_ENT + e] - NE, c1), 0);
        {
            int k = c0;
            for (; k + 4 <= c1; k += 4) {
#pragma unroll
                for (int q = 0; q < 4; ++q) {
                    int2 t2 = rc[k + q];                   // uniform -> s_load
                    agg += __int_as_float(t2.y) *
                           __half2float(usr16_cur[(t2.x << 6) + lane]);
                }
            }
            for (; k < c1; ++k) {
                int2 t2 = rc[k];
                agg += __int_as_float(t2.y) *
                       __half2float(usr16_cur[(t2.x << 6) + lane]);
            }
        }

        // --- normalize + residual (+ next-hop sq from registers) ---
        float s = wave_sum(agg * agg);
        float y = agg / fmaxf(sqrtf(s), 1e-12f);
        int oi = (e << 6) + lane;
        if (!LAST) {
            ent16_next[oi] = __float2half(y);
            float y2 = y * y;
            float mine = 0.f;
#pragma unroll
            for (int rt = 0; rt < NREL9; ++rt) {
                float r = wt[(rt << 6) + lane];
                float sv = wave_sum(y2 * r * r);
                if (lane == rt) mine = sv;
            }
            if (lane < NREL9) sq_out[e * NREL9 + lane] = mine;
        }
        if (FIRST) out_ent[oi] = ent_res_base[oi] + y;
        else       out_ent[oi] += y;
    } else {
        // ================= user role: one wave per user ==================
        int u = __builtin_amdgcn_readfirstlane(((b - EG) * 256 + (int)threadIdx.x) >> 6);
        int s1 = min(start[2 * N_ENT + u + 1] - 2 * NE, NNZV);
        int s0 = max(min(start[2 * N_ENT + u] - 2 * NE, s1), 0);
        float accA = 0.f, accB = 0.f;
        {
            int k = s0;
            for (; k + 4 <= s1; k += 4) {
#pragma unroll
                for (int q = 0; q < 4; ++q) {
                    int2 t2 = cv[k + q];                   // uniform -> s_load
                    float prod = __int_as_float(t2.y) *
                                 __half2float(ent16_cur[(t2.x << 6) + lane]);
                    if (q & 1) accB += prod; else accA += prod;
                }
            }
            for (; k < s1; ++k) {
                int2 t2 = cv[k];
                accA += __int_as_float(t2.y) *
                        __half2float(ent16_cur[(t2.x << 6) + lane]);
            }
        }
        float acc = accA + accB;
        float s = wave_sum(acc * acc);
        float y = acc / fmaxf(sqrtf(s), 1e-12f);
        int oi = (u << 6) + lane;
        if (!LAST) usr16_next[oi] = __float2half(y);
        if (FIRST) out_usr[oi] = usr_res_base[oi] + y;
        else       out_usr[oi] += y;
    }
}

extern "C" void kernel_launch(void* const* d_in, const int* in_sizes, int n_in,
                              void* d_out, int out_size, void* d_ws, size_t ws_size,
                              hipStream_t stream)
{
    const float* user_emb   = (const float*)d_in[0];
    const float* entity_emb = (const float*)d_in[1];
    const float* wt         = (const float*)d_in[2];
    const float* inter_vals = (const float*)d_in[3];
    const int*   edge_index = (const int*)d_in[4];
    const int*   etype      = (const int*)d_in[5];
    const int*   inter_rows = (const int*)d_in[6];
    const int*   inter_cols = (const int*)d_in[7];
    const int* head  = edge_index;
    const int* tailp = edge_index + NE;

    // Workspace layout (~86 MB). ORDER MATTERS: ent16_b and usr16_b are
    // adjacent so priv (25.2MB) can alias them — priv dies after
    // k_scatter_lds; ent16_b/usr16_b are first written by hop 1.
    __half* ent16_a = (__half*)d_ws;                         // N_ENT*64 halves
    __half* usr16_a = ent16_a + (size_t)N_ENT * CDIM;        // N_USR*64
    __half* ent16_b = usr16_a + (size_t)N_USR * CDIM;        // N_ENT*64
    __half* usr16_b = ent16_b + (size_t)N_ENT * CDIM;        // N_USR*64
    int2*  rc     = (int2*)(usr16_b + (size_t)N_USR * CDIM); // NNZ
    int2*  cv     = rc + NNZV;                               // NNZ
    int*   pk_h   = (int*)(cv + NNZV);                       // NE
    int*   cnt    = pk_h + NE;                               // NTOT
    int*   start  = cnt + NTOT;                              // NTOT+1
    int*   bsum   = start + NTOT + 1;                        // SCAN_B
    float* sq_a   = (float*)(bsum + SCAN_B);                 // N_ENT*9
    float* sq_b   = sq_a + (size_t)N_ENT * NREL9;            // N_ENT*9
    int*   priv   = (int*)ent16_b;              // HIST_BLKS*SLICE_K (25.2MB)

    float* out_ent = (float*)d_out;
    float* out_usr = out_ent + (size_t)N_ENT * CDIM;

    // ---- CSR build (zero global atomics) + hop-1 prep ----
    k_hist_lds<<<HIST_BLKS, 256, 0, stream>>>(head, inter_cols, inter_rows, priv);
    k_prepreduce<<<RB + EG + UCVT, 256, 0, stream>>>(
        priv, cnt, entity_emb, user_emb, wt, ent16_a, usr16_a, sq_a);
    k_bsum<<<SCAN_B, 1024, 0, stream>>>(cnt, bsum);
    k_scan_small<<<1, 512, 0, stream>>>(bsum);
    k_scan_apply<<<SCAN_B, 1024, 0, stream>>>(cnt, bsum, start);
    k_scatter_lds<<<HIST_BLKS, 256, 0, stream>>>(
        head, tailp, etype, inter_rows, inter_cols, inter_vals,
        start, priv, pk_h, rc, cv);

    // ---- hop 1: gather fp16_a; write fp16_b + sq_b; out = input + y1 ----
    k_hop<true, false><<<EG + UG, 256, 0, stream>>>(
        ent16_a, usr16_a, entity_emb, user_emb, wt, start, pk_h, sq_a, rc, cv,
        ent16_b, usr16_b, sq_b, out_ent, out_usr);

    // ---- hop 2: gather fp16_b; out += y2 ----
    k_hop<false, true><<<EG + UG, 256, 0, stream>>>(
        ent16_b, usr16_b, nullptr, nullptr, wt, start, pk_h, sq_b, rc, cv,
        nullptr, nullptr, nullptr, out_ent, out_usr);
}